// Round 13
// baseline (217.772 us; speedup 1.0000x reference)
//
#include <hip/hip_runtime.h>
#include <hip/hip_bf16.h>

#define IN_F 1024
#define OUT_F 1024
#define KTOT (IN_F * 9)   // 9216: channel-major, k = c*1024 + i, c=0 is silu
#define M_ROWS 8192

#define BK 64
#define NT (KTOT / BK)    // 144 kt64-tiles; BK=32 tiles: 288 total, 144/K-half
#define NT_H (NT / 2)

#define A_TILE_E 16384    // elements per A kt64-tile of a 256-row panel (32 KB)
#define B_TILE_E 8192     // elements per B kt64-tile of a 128-col panel (16 KB)

typedef short bf16x8 __attribute__((ext_vector_type(8)));
typedef int   i32x4  __attribute__((ext_vector_type(4)));
typedef float f32x4  __attribute__((ext_vector_type(4)));

#define AS1 __attribute__((address_space(1)))
#define AS3 __attribute__((address_space(3)))

// ---------------------------------------------------------------- basis eval
__device__ __forceinline__ void kan_basis_fast(
    float xv, const float* __restrict__ g,
    const float* __restrict__ inv1, const float* __restrict__ inv2,
    const float* __restrict__ inv3, float* __restrict__ out) {
  float b[11];
#pragma unroll
  for (int j = 0; j < 11; ++j)
    b[j] = (xv >= g[j] && xv < g[j + 1]) ? 1.0f : 0.0f;
#pragma unroll
  for (int j = 0; j < 10; ++j)
    b[j] = (xv - g[j]) * inv1[j] * b[j] + (g[j + 2] - xv) * inv1[j + 1] * b[j + 1];
#pragma unroll
  for (int j = 0; j < 9; ++j)
    b[j] = (xv - g[j]) * inv2[j] * b[j] + (g[j + 3] - xv) * inv2[j + 1] * b[j + 1];
#pragma unroll
  for (int j = 0; j < 8; ++j)
    b[j] = (xv - g[j]) * inv3[j] * b[j] + (g[j + 4] - xv) * inv3[j + 1] * b[j + 1];
#pragma unroll
  for (int j = 0; j < 8; ++j) out[j] = b[j];
}

// ------------------------------------------------- A expansion (fp32 -> bf16)
// Frag-ordered A (verified R9-R12): frag = (((bm*NT+kt)*4+wm4)*4+m)*2+kk,
// lane = lhi*16+l15 holds A[row][k=kt*64+kk*32+lhi*8+j].
__global__ __launch_bounds__(256) void expand_a(
    const float* __restrict__ x, const float* __restrict__ grid,
    __hip_bfloat16* __restrict__ A, int row0, int nrows) {
  const int tid = threadIdx.x;
  const int lane = tid & 63;
  const int wvx = tid >> 6;            // 0..3 : i-subblock
  const int l15 = lane & 15;
  const int lhi = lane >> 4;

  const int nb = blockIdx.x >> 3;      // 16-row group (local)
  const int ib = blockIdx.x & 7;       // 128-wide i group
  const int n_l = nb * 16 + l15;       // local row
  const int i0 = ib * 128 + wvx * 32 + lhi * 8;

  const int bm = n_l >> 8, wm = (n_l >> 6) & 3, m = (n_l >> 4) & 3;

  float g[12];
  const float* gp = grid + (size_t)i0 * 12;   // rows identical by construction
#pragma unroll
  for (int j = 0; j < 12; ++j) g[j] = gp[j];
  float inv1[11], inv2[10], inv3[9];
#pragma unroll
  for (int j = 0; j < 11; ++j) inv1[j] = 1.0f / (g[j + 1] - g[j]);
#pragma unroll
  for (int j = 0; j < 10; ++j) inv2[j] = 1.0f / (g[j + 2] - g[j]);
#pragma unroll
  for (int j = 0; j < 9; ++j)  inv3[j] = 1.0f / (g[j + 3] - g[j]);

  const float* xp = x + (size_t)(row0 + n_l) * IN_F + i0;
  float xs[8];
  *(f32x4*)&xs[0] = *(const f32x4*)xp;
  *(f32x4*)&xs[4] = *(const f32x4*)(xp + 4);

  bf16x8 out[9];
#pragma unroll
  for (int j = 0; j < 8; ++j) {
    float xv = xs[j];
    float bas[8];
    kan_basis_fast(xv, g, inv1, inv2, inv3, bas);
    float s = xv / (1.0f + __expf(-xv));
    out[0][j] = (short)__bfloat16_as_ushort(__float2bfloat16(s));
#pragma unroll
    for (int c = 0; c < 8; ++c)
      out[c + 1][j] = (short)__bfloat16_as_ushort(__float2bfloat16(bas[c]));
  }

#pragma unroll
  for (int c = 0; c < 9; ++c) {
    int k0 = c * IN_F + i0;            // wave-uniform kt,kk per c
    int kt = k0 >> 6;
    int kk = (k0 >> 5) & 1;
    size_t frag = ((((size_t)bm * NT + kt) * 4 + wm) * 4 + m) * 2 + kk;
    *(bf16x8*)(A + frag * 512 + lane * 8) = out[c];
  }
}

// --------------------------------------------------- B packing (fp32 -> bf16)
// Frag-ordered B (verified R11/R12): frag = ((obn*NT+kt)*8+colg)*2+kk over
// 128-col panels obn (0..7).
__global__ __launch_bounds__(256) void pack_b(
    const float* __restrict__ bw, const float* __restrict__ sw,
    const float* __restrict__ sc, __hip_bfloat16* __restrict__ B) {
  const int tid = threadIdx.x;
  const int lane = tid & 63;
  const int wid = blockIdx.x * 4 + (tid >> 6);   // 0..2047
  const int og = wid >> 5;           // 0..63: o-group of 16
  const int ib32 = wid & 31;         // 0..31: 32-wide i block
  const int obn = og >> 3, colg = og & 7;
  const int l15 = lane & 15, lhi = lane >> 4;
  const int o = og * 16 + l15;
  const int i0 = ib32 * 32 + lhi * 8;

  float bwv[8], scv[8];
  const float* bp = bw + (size_t)o * IN_F + i0;
  const float* sp = sc + (size_t)o * IN_F + i0;
  *(f32x4*)&bwv[0] = *(const f32x4*)bp;
  *(f32x4*)&bwv[4] = *(const f32x4*)(bp + 4);
  *(f32x4*)&scv[0] = *(const f32x4*)sp;
  *(f32x4*)&scv[4] = *(const f32x4*)(sp + 4);

  bf16x8 out[9];
#pragma unroll
  for (int j = 0; j < 8; ++j) {
    out[0][j] = (short)__bfloat16_as_ushort(__float2bfloat16(bwv[j]));
    const float* swp = sw + ((size_t)o * IN_F + i0 + j) * 8;
    float swv[8];
    *(f32x4*)&swv[0] = *(const f32x4*)swp;
    *(f32x4*)&swv[4] = *(const f32x4*)(swp + 4);
#pragma unroll
    for (int c = 0; c < 8; ++c)
      out[c + 1][j] = (short)__bfloat16_as_ushort(__float2bfloat16(swv[c] * scv[j]));
  }

#pragma unroll
  for (int c = 0; c < 9; ++c) {
    int kt = c * 16 + (ib32 >> 1);     // k0 = c*1024 + ib32*32
    int kk = ib32 & 1;
    size_t frag = ((size_t)obn * NT + kt) * 16 + colg * 2 + kk;
    *(bf16x8*)(B + frag * 512 + lane * 8) = out[c];
  }
}

// -------------------------------------------------------------- bf16 GEMM BT
// v13: 256x256 tile, BK=32, split-K=2. 4-slot 32KB ring (128 KB) staged 2
// ahead, counted vmcnt(4), ONE barrier/tile, ping-pong frag regs (v11 flow).
// 8 waves @128x64: LDS reads 3 B/C-elem. Frag-ordered A/B, no swizzle.
// Epilogue: fp32 atomicAdd into memset-zeroed C (2 commutative adds/elem).

__device__ __forceinline__ void gld16(const __hip_bfloat16* g, __hip_bfloat16* l) {
  __builtin_amdgcn_global_load_lds((AS1 void*)g, (AS3 void*)l, 16, 0, 0);
}

#define DSRO(dst, addr, IMM)                                               \
  asm volatile("ds_read_b128 %0, %1 offset:" #IMM : "=v"(dst) : "v"(addr))

#define SB __builtin_amdgcn_sched_barrier(0)

#define READ_A8(d, aA) do {                                                \
    DSRO(d[0], aA, 0);     DSRO(d[1], aA, 1024);                           \
    DSRO(d[2], aA, 2048);  DSRO(d[3], aA, 3072);                           \
    DSRO(d[4], aA, 4096);  DSRO(d[5], aA, 5120);                           \
    DSRO(d[6], aA, 6144);  DSRO(d[7], aA, 7168);                           \
  } while (0)
#define READ_B4(d, bA) do {                                                \
    DSRO(d[0], bA, 0);     DSRO(d[1], bA, 1024);                           \
    DSRO(d[2], bA, 2048);  DSRO(d[3], bA, 3072);                           \
  } while (0)

#define MFMA32(sA, sB) do {                                                \
    __builtin_amdgcn_s_setprio(1);                                         \
    _Pragma("unroll")                                                      \
    for (int m_ = 0; m_ < 8; ++m_)                                         \
      _Pragma("unroll")                                                    \
      for (int n_ = 0; n_ < 4; ++n_)                                       \
        acc[m_][n_] = __builtin_amdgcn_mfma_f32_16x16x32_bf16(             \
            sA[m_], sB[n_], acc[m_][n_], 0, 0, 0);                         \
    __builtin_amdgcn_s_setprio(0);                                         \
  } while (0)

// stage one BK=32 tile (4 gld16/wave): A 16 KB + B 2x8 KB
#define STAGE13(SLOT, GA_, GB_) do {                                       \
    __hip_bfloat16* d_ = ldsP + (SLOT) * 16384;                            \
    gld16(aPw + (GA_),         d_ + wv * 512);                             \
    gld16(aPw + (GA_) + 8192,  d_ + 4096 + wv * 512);                      \
    gld16(bP0w + (GB_),        d_ + 8192 + wv * 512);                      \
    gld16(bP1w + (GB_),        d_ + 12288 + wv * 512);                     \
  } while (0)

#define VM4 asm volatile("s_waitcnt vmcnt(4)" ::: "memory")
#define VM0 asm volatile("s_waitcnt vmcnt(0)" ::: "memory")
#define LGK0 asm volatile("s_waitcnt lgkmcnt(0)" ::: "memory")

// body tile t: FA/FB preloaded; stage t+2; publish t+1; read t+1 into GA/GB
#define BODY13(FA, FB, GA, GB, SN, STAGE_, VMW_) do {                      \
    STAGE_;                                                                \
    SB;                                                                    \
    VMW_;                                                                  \
    SB;                                                                    \
    LGK0;                                                                  \
    SB;                                                                    \
    __builtin_amdgcn_s_barrier();                                          \
    SB;                                                                    \
    READ_A8(GA, aRdB + (SN) * 32768u);                                     \
    READ_B4(GB, bRdB + (SN) * 32768u);                                     \
    SB;                                                                    \
    MFMA32(FA, FB);                                                        \
    SB;                                                                    \
  } while (0)

__global__ __launch_bounds__(512, 2) void gemm_v13(
    const __hip_bfloat16* __restrict__ A, const __hip_bfloat16* __restrict__ B,
    float* __restrict__ C) {
  __shared__ __align__(16) __hip_bfloat16 S[4][16384];  // 4 x 32 KB

  // bijective XCD swizzle: 8 consecutive L share bm -> A-panel L2 reuse
  const int nwg = gridDim.x;            // (M/256)*8, %8 == 0
  const int q = nwg >> 3;
  const int L = (blockIdx.x & 7) * q + (blockIdx.x >> 3);
  const int bm = L >> 3;
  const int khalf = (L >> 2) & 1;
  const int bn2 = L & 3;                // 256-col block

  const int tid = threadIdx.x;
  const int lane = tid & 63;
  const int wv = tid >> 6;            // 0..7
  const int wm = wv >> 2;             // 0..1 (128-row half)
  const int wn = wv & 3;              // 0..3 (64-col quarter)
  const int l15 = lane & 15, lhi = lane >> 4;

  // ---- staging pointers (元素): per-wave lane slice of each 1 KB frag
  const __hip_bfloat16* aPw =
      A + ((size_t)bm * NT + khalf * NT_H) * A_TILE_E + wv * 1024 + lane * 8;
  const __hip_bfloat16* bP0w =
      B + ((size_t)(2 * bn2) * NT + khalf * NT_H) * B_TILE_E + wv * 1024 + lane * 8;
  const __hip_bfloat16* bP1w =
      B + ((size_t)(2 * bn2 + 1) * NT + khalf * NT_H) * B_TILE_E + wv * 1024 + lane * 8;
  __hip_bfloat16* ldsP = &S[0][0];

  // ---- fragment read byte-bases (slot added per body as compile-time const)
  const uint32_t ldsB = (uint32_t)(uintptr_t)(AS3 const void*)&S[0][0];
  const uint32_t aRdB = ldsB + wm * 8192 + lane * 16;
  const uint32_t bRdB = ldsB + 16384 + wn * 4096 + lane * 16;

  f32x4 acc[8][4];
#pragma unroll
  for (int m = 0; m < 8; ++m)
#pragma unroll
    for (int n = 0; n < 4; ++n) acc[m][n] = f32x4{0.f, 0.f, 0.f, 0.f};

  bf16x8 fa[8], fb[4];   // even-tile frags
  bf16x8 ga[8], gb[4];   // odd-tile frags

  // ---- prologue: stage tiles 0,1 -> slots 0,1; publish 0; preload frags(0)
  STAGE13(0, 0, 0);                                   // vm 4
  STAGE13(1, 512, 512);                               // vm 8
  VM4;                                                // tile 0 landed
  SB;
  __builtin_amdgcn_s_barrier();
  SB;
  READ_A8(fa, aRdB);
  READ_B4(fb, bRdB);                                  // lgkm 12
  SB;
  aPw += 16384; bP0w += 8192; bP1w += 8192;           // -> kt64 block of tile 2

#pragma unroll 1
  for (int tt = 0; tt < 35; ++tt) {                   // t = 4tt .. 4tt+3
    BODY13(fa, fb, ga, gb, 1, STAGE13(2, 0, 0), VM4);
    BODY13(ga, gb, fa, fb, 2, STAGE13(3, 512, 512), VM4);
    BODY13(fa, fb, ga, gb, 3, STAGE13(0, 16384, 8192), VM4);
    BODY13(ga, gb, fa, fb, 0, STAGE13(1, 16896, 8704), VM4);
    aPw += 32768; bP0w += 16384; bP1w += 16384;
  }
  // t = 140, 141: stage 142,143
  BODY13(fa, fb, ga, gb, 1, STAGE13(2, 0, 0), VM4);
  BODY13(ga, gb, fa, fb, 2, STAGE13(3, 512, 512), VM4);
  // t = 142: no stage; drain last DMA
  BODY13(fa, fb, ga, gb, 3, ;, VM0);
  // t = 143: last
  LGK0;
  SB;
  MFMA32(ga, gb);

  // ---- epilogue: atomicAdd into C (split-K partner adds the other half)
  // C/D mapping col = lane&15, row = (lane>>4)*4 + reg  [m89-verified]
#pragma unroll
  for (int m = 0; m < 8; ++m)
#pragma unroll
    for (int n = 0; n < 4; ++n) {
      int col = bn2 * 256 + wn * 64 + n * 16 + l15;
      int row0 = bm * 256 + wm * 128 + m * 16 + lhi * 4;
#pragma unroll
      for (int j = 0; j < 4; ++j)
        atomicAdd(&C[(size_t)(row0 + j) * OUT_F + col], acc[m][n][j]);
    }
}

// ------------------------------------------------ naive fallback (insurance)
__global__ __launch_bounds__(256) void kan_naive(
    const float* __restrict__ x, const float* __restrict__ grid,
    const float* __restrict__ bw, const float* __restrict__ sw,
    const float* __restrict__ sc, float* __restrict__ out) {
  __shared__ float s_act[IN_F];
  __shared__ float s_bas[IN_F * 8];
  int n = blockIdx.x;
  for (int i = threadIdx.x; i < IN_F; i += 256) {
    float xv = x[(size_t)n * IN_F + i];
    float g[12];
    const float* gp = grid + i * 12;
#pragma unroll
    for (int t = 0; t < 12; ++t) g[t] = gp[t];
    float b[11];
#pragma unroll
    for (int j = 0; j < 11; ++j)
      b[j] = (xv >= g[j] && xv < g[j + 1]) ? 1.0f : 0.0f;
#pragma unroll
    for (int k = 1; k <= 3; ++k)
#pragma unroll
      for (int j = 0; j < 11 - k; ++j) {
        float left = (xv - g[j]) / (g[j + k] - g[j]);
        float right = (g[j + k + 1] - xv) / (g[j + k + 1] - g[j + 1]);
        b[j] = left * b[j] + right * b[j + 1];
      }
    s_act[i] = xv / (1.0f + __expf(-xv));
#pragma unroll
    for (int c = 0; c < 8; ++c) s_bas[i * 8 + c] = b[c];
  }
  __syncthreads();
  for (int o = threadIdx.x; o < OUT_F; o += 256) {
    float acc = 0.f;
    const float* bwo = bw + (size_t)o * IN_F;
    const float* swo = sw + (size_t)o * IN_F * 8;
    const float* sco = sc + (size_t)o * IN_F;
    for (int i = 0; i < IN_F; ++i) {
      acc += s_act[i] * bwo[i];
      float p = 0.f;
#pragma unroll
      for (int c = 0; c < 8; ++c) p += s_bas[i * 8 + c] * swo[i * 8 + c];
      acc += p * sco[i];
    }
    out[(size_t)n * OUT_F + o] = acc;
  }
}

// ---------------------------------------------------------------- launch
extern "C" void kernel_launch(void* const* d_in, const int* in_sizes, int n_in,
                              void* d_out, int out_size, void* d_ws, size_t ws_size,
                              hipStream_t stream) {
  const float* x  = (const float*)d_in[0];
  const float* grid = (const float*)d_in[1];
  const float* bw = (const float*)d_in[2];
  const float* sw = (const float*)d_in[3];
  const float* sc = (const float*)d_in[4];
  float* out = (float*)d_out;

  const size_t Bbytes = (size_t)OUT_F * KTOT * 2;   // 18.9 MB
  const size_t rowBytes = (size_t)KTOT * 2;         // 18 KB / A-row

  if (ws_size >= Bbytes + 256 * rowBytes) {
    __hip_bfloat16* Bp = (__hip_bfloat16*)d_ws;
    __hip_bfloat16* Ap = (__hip_bfloat16*)((char*)d_ws + Bbytes);
    size_t arows = (ws_size - Bbytes) / rowBytes;
    int chunk = (int)((arows / 256) * 256);
    if (chunk > M_ROWS) chunk = M_ROWS;

    hipMemsetAsync(d_out, 0, (size_t)out_size * sizeof(float), stream);
    pack_b<<<OUT_F * 128 / 256, 256, 0, stream>>>(bw, sw, sc, Bp);
    for (int r0 = 0; r0 < M_ROWS; r0 += chunk) {
      int rows = M_ROWS - r0 < chunk ? M_ROWS - r0 : chunk;   // multiple of 256
      expand_a<<<(rows / 16) * 8, 256, 0, stream>>>(x, grid, Ap, r0, rows);
      gemm_v13<<<(rows / 256) * 8, 512, 0, stream>>>(Ap, Bp, out + (size_t)r0 * OUT_F);
    }
  } else {
    kan_naive<<<M_ROWS, 256, 0, stream>>>(x, grid, bw, sw, sc, out);
  }
}

// Round 14
// 192.449 us; speedup vs baseline: 1.1316x; 1.1316x over previous
//
#include <hip/hip_runtime.h>
#include <hip/hip_bf16.h>

#define IN_F 1024
#define OUT_F 1024
#define KTOT (IN_F * 9)   // 9216: channel-major, k = c*1024 + i, c=0 is silu
#define M_ROWS 8192

#define BK 64
#define NT (KTOT / BK)    // 144 kt64-tiles; BK=32 tiles: 288 total, 144/K-half
#define NT_H (NT / 2)

#define A_TILE_E 16384    // elements per A kt64-tile of a 256-row panel (32 KB)
#define B_TILE_E 8192     // elements per B kt64-tile of a 128-col panel (16 KB)

typedef short bf16x8 __attribute__((ext_vector_type(8)));
typedef int   i32x4  __attribute__((ext_vector_type(4)));
typedef float f32x4  __attribute__((ext_vector_type(4)));

#define AS1 __attribute__((address_space(1)))
#define AS3 __attribute__((address_space(3)))

// ---------------------------------------------------------------- basis eval
__device__ __forceinline__ void kan_basis_fast(
    float xv, const float* __restrict__ g,
    const float* __restrict__ inv1, const float* __restrict__ inv2,
    const float* __restrict__ inv3, float* __restrict__ out) {
  float b[11];
#pragma unroll
  for (int j = 0; j < 11; ++j)
    b[j] = (xv >= g[j] && xv < g[j + 1]) ? 1.0f : 0.0f;
#pragma unroll
  for (int j = 0; j < 10; ++j)
    b[j] = (xv - g[j]) * inv1[j] * b[j] + (g[j + 2] - xv) * inv1[j + 1] * b[j + 1];
#pragma unroll
  for (int j = 0; j < 9; ++j)
    b[j] = (xv - g[j]) * inv2[j] * b[j] + (g[j + 3] - xv) * inv2[j + 1] * b[j + 1];
#pragma unroll
  for (int j = 0; j < 8; ++j)
    b[j] = (xv - g[j]) * inv3[j] * b[j] + (g[j + 4] - xv) * inv3[j + 1] * b[j + 1];
#pragma unroll
  for (int j = 0; j < 8; ++j) out[j] = b[j];
}

// ------------------------------------------------- A expansion (fp32 -> bf16)
// Frag-ordered A (verified R9-R13): frag = (((bm*NT+kt)*4+wm4)*4+m)*2+kk,
// lane = lhi*16+l15 holds A[row][k=kt*64+kk*32+lhi*8+j].
__global__ __launch_bounds__(256) void expand_a(
    const float* __restrict__ x, const float* __restrict__ grid,
    __hip_bfloat16* __restrict__ A, int row0, int nrows) {
  const int tid = threadIdx.x;
  const int lane = tid & 63;
  const int wvx = tid >> 6;            // 0..3 : i-subblock
  const int l15 = lane & 15;
  const int lhi = lane >> 4;

  const int nb = blockIdx.x >> 3;      // 16-row group (local)
  const int ib = blockIdx.x & 7;       // 128-wide i group
  const int n_l = nb * 16 + l15;       // local row
  const int i0 = ib * 128 + wvx * 32 + lhi * 8;

  const int bm = n_l >> 8, wm = (n_l >> 6) & 3, m = (n_l >> 4) & 3;

  float g[12];
  const float* gp = grid + (size_t)i0 * 12;   // rows identical by construction
#pragma unroll
  for (int j = 0; j < 12; ++j) g[j] = gp[j];
  float inv1[11], inv2[10], inv3[9];
#pragma unroll
  for (int j = 0; j < 11; ++j) inv1[j] = 1.0f / (g[j + 1] - g[j]);
#pragma unroll
  for (int j = 0; j < 10; ++j) inv2[j] = 1.0f / (g[j + 2] - g[j]);
#pragma unroll
  for (int j = 0; j < 9; ++j)  inv3[j] = 1.0f / (g[j + 3] - g[j]);

  const float* xp = x + (size_t)(row0 + n_l) * IN_F + i0;
  float xs[8];
  *(f32x4*)&xs[0] = *(const f32x4*)xp;
  *(f32x4*)&xs[4] = *(const f32x4*)(xp + 4);

  bf16x8 out[9];
#pragma unroll
  for (int j = 0; j < 8; ++j) {
    float xv = xs[j];
    float bas[8];
    kan_basis_fast(xv, g, inv1, inv2, inv3, bas);
    float s = xv / (1.0f + __expf(-xv));
    out[0][j] = (short)__bfloat16_as_ushort(__float2bfloat16(s));
#pragma unroll
    for (int c = 0; c < 8; ++c)
      out[c + 1][j] = (short)__bfloat16_as_ushort(__float2bfloat16(bas[c]));
  }

#pragma unroll
  for (int c = 0; c < 9; ++c) {
    int k0 = c * IN_F + i0;            // wave-uniform kt,kk per c
    int kt = k0 >> 6;
    int kk = (k0 >> 5) & 1;
    size_t frag = ((((size_t)bm * NT + kt) * 4 + wm) * 4 + m) * 2 + kk;
    *(bf16x8*)(A + frag * 512 + lane * 8) = out[c];
  }
}

// --------------------------------------------------- B packing (fp32 -> bf16)
// Frag-ordered B (verified R11-R13): frag = ((obn*NT+kt)*8+colg)*2+kk over
// 128-col panels obn (0..7).
__global__ __launch_bounds__(256) void pack_b(
    const float* __restrict__ bw, const float* __restrict__ sw,
    const float* __restrict__ sc, __hip_bfloat16* __restrict__ B) {
  const int tid = threadIdx.x;
  const int lane = tid & 63;
  const int wid = blockIdx.x * 4 + (tid >> 6);   // 0..2047
  const int og = wid >> 5;           // 0..63: o-group of 16
  const int ib32 = wid & 31;         // 0..31: 32-wide i block
  const int obn = og >> 3, colg = og & 7;
  const int l15 = lane & 15, lhi = lane >> 4;
  const int o = og * 16 + l15;
  const int i0 = ib32 * 32 + lhi * 8;

  float bwv[8], scv[8];
  const float* bp = bw + (size_t)o * IN_F + i0;
  const float* sp = sc + (size_t)o * IN_F + i0;
  *(f32x4*)&bwv[0] = *(const f32x4*)bp;
  *(f32x4*)&bwv[4] = *(const f32x4*)(bp + 4);
  *(f32x4*)&scv[0] = *(const f32x4*)sp;
  *(f32x4*)&scv[4] = *(const f32x4*)(sp + 4);

  bf16x8 out[9];
#pragma unroll
  for (int j = 0; j < 8; ++j) {
    out[0][j] = (short)__bfloat16_as_ushort(__float2bfloat16(bwv[j]));
    const float* swp = sw + ((size_t)o * IN_F + i0 + j) * 8;
    float swv[8];
    *(f32x4*)&swv[0] = *(const f32x4*)swp;
    *(f32x4*)&swv[4] = *(const f32x4*)(swp + 4);
#pragma unroll
    for (int c = 0; c < 8; ++c)
      out[c + 1][j] = (short)__bfloat16_as_ushort(__float2bfloat16(swv[c] * scv[j]));
  }

#pragma unroll
  for (int c = 0; c < 9; ++c) {
    int kt = c * 16 + (ib32 >> 1);     // k0 = c*1024 + ib32*32
    int kk = ib32 & 1;
    size_t frag = ((size_t)obn * NT + kt) * 16 + colg * 2 + kk;
    *(bf16x8*)(B + frag * 512 + lane * 8) = out[c];
  }
}

// -------------------------------------------------------------- bf16 GEMM BT
// v14: v13's verified 256x256/BK=32/split-K=2 body (4-slot 32KB ring staged
// 2 ahead, counted vmcnt(4), ONE barrier/tile, ping-pong frag regs) with the
// atomic epilogue replaced: kh=1 blocks store C directly (cover ALL of C);
// kh=0 blocks store 256x256 fp32 partials to P; reduce2 does C += P.

__device__ __forceinline__ void gld16(const __hip_bfloat16* g, __hip_bfloat16* l) {
  __builtin_amdgcn_global_load_lds((AS1 void*)g, (AS3 void*)l, 16, 0, 0);
}

#define DSRO(dst, addr, IMM)                                               \
  asm volatile("ds_read_b128 %0, %1 offset:" #IMM : "=v"(dst) : "v"(addr))

#define SB __builtin_amdgcn_sched_barrier(0)

#define READ_A8(d, aA) do {                                                \
    DSRO(d[0], aA, 0);     DSRO(d[1], aA, 1024);                           \
    DSRO(d[2], aA, 2048);  DSRO(d[3], aA, 3072);                           \
    DSRO(d[4], aA, 4096);  DSRO(d[5], aA, 5120);                           \
    DSRO(d[6], aA, 6144);  DSRO(d[7], aA, 7168);                           \
  } while (0)
#define READ_B4(d, bA) do {                                                \
    DSRO(d[0], bA, 0);     DSRO(d[1], bA, 1024);                           \
    DSRO(d[2], bA, 2048);  DSRO(d[3], bA, 3072);                           \
  } while (0)

#define MFMA32(sA, sB) do {                                                \
    __builtin_amdgcn_s_setprio(1);                                         \
    _Pragma("unroll")                                                      \
    for (int m_ = 0; m_ < 8; ++m_)                                         \
      _Pragma("unroll")                                                    \
      for (int n_ = 0; n_ < 4; ++n_)                                       \
        acc[m_][n_] = __builtin_amdgcn_mfma_f32_16x16x32_bf16(             \
            sA[m_], sB[n_], acc[m_][n_], 0, 0, 0);                         \
    __builtin_amdgcn_s_setprio(0);                                         \
  } while (0)

#define STAGE14(SLOT, GA_, GB_) do {                                       \
    __hip_bfloat16* d_ = ldsP + (SLOT) * 16384;                            \
    gld16(aPw + (GA_),         d_ + wv * 512);                             \
    gld16(aPw + (GA_) + 8192,  d_ + 4096 + wv * 512);                      \
    gld16(bP0w + (GB_),        d_ + 8192 + wv * 512);                      \
    gld16(bP1w + (GB_),        d_ + 12288 + wv * 512);                     \
  } while (0)

#define VM4 asm volatile("s_waitcnt vmcnt(4)" ::: "memory")
#define VM0 asm volatile("s_waitcnt vmcnt(0)" ::: "memory")
#define LGK0 asm volatile("s_waitcnt lgkmcnt(0)" ::: "memory")

#define BODY14(FA, FB, GA, GB, SN, STAGE_, VMW_) do {                      \
    STAGE_;                                                                \
    SB;                                                                    \
    VMW_;                                                                  \
    SB;                                                                    \
    LGK0;                                                                  \
    SB;                                                                    \
    __builtin_amdgcn_s_barrier();                                          \
    SB;                                                                    \
    READ_A8(GA, aRdB + (SN) * 32768u);                                     \
    READ_B4(GB, bRdB + (SN) * 32768u);                                     \
    SB;                                                                    \
    MFMA32(FA, FB);                                                        \
    SB;                                                                    \
  } while (0)

template <int ATOMIC>
__global__ __launch_bounds__(512, 2) void gemm_v14(
    const __hip_bfloat16* __restrict__ A, const __hip_bfloat16* __restrict__ B,
    float* __restrict__ C, float* __restrict__ P) {
  __shared__ __align__(16) __hip_bfloat16 S[4][16384];  // 4 x 32 KB

  // bijective XCD swizzle: 8 consecutive L share bm -> A-panel L2 reuse
  const int nwg = gridDim.x;            // (M/256)*8, %8 == 0
  const int q = nwg >> 3;
  const int L = (blockIdx.x & 7) * q + (blockIdx.x >> 3);
  const int bm = L >> 3;
  const int khalf = (L >> 2) & 1;
  const int bn2 = L & 3;                // 256-col block

  const int tid = threadIdx.x;
  const int lane = tid & 63;
  const int wv = tid >> 6;            // 0..7
  const int wm = wv >> 2;             // 0..1 (128-row half)
  const int wn = wv & 3;              // 0..3 (64-col quarter)
  const int l15 = lane & 15, lhi = lane >> 4;

  const __hip_bfloat16* aPw =
      A + ((size_t)bm * NT + khalf * NT_H) * A_TILE_E + wv * 1024 + lane * 8;
  const __hip_bfloat16* bP0w =
      B + ((size_t)(2 * bn2) * NT + khalf * NT_H) * B_TILE_E + wv * 1024 + lane * 8;
  const __hip_bfloat16* bP1w =
      B + ((size_t)(2 * bn2 + 1) * NT + khalf * NT_H) * B_TILE_E + wv * 1024 + lane * 8;
  __hip_bfloat16* ldsP = &S[0][0];

  const uint32_t ldsB = (uint32_t)(uintptr_t)(AS3 const void*)&S[0][0];
  const uint32_t aRdB = ldsB + wm * 8192 + lane * 16;
  const uint32_t bRdB = ldsB + 16384 + wn * 4096 + lane * 16;

  f32x4 acc[8][4];
#pragma unroll
  for (int m = 0; m < 8; ++m)
#pragma unroll
    for (int n = 0; n < 4; ++n) acc[m][n] = f32x4{0.f, 0.f, 0.f, 0.f};

  bf16x8 fa[8], fb[4];
  bf16x8 ga[8], gb[4];

  // ---- prologue: stage tiles 0,1 -> slots 0,1; publish 0; preload frags(0)
  STAGE14(0, 0, 0);
  STAGE14(1, 512, 512);
  VM4;
  SB;
  __builtin_amdgcn_s_barrier();
  SB;
  READ_A8(fa, aRdB);
  READ_B4(fb, bRdB);
  SB;
  aPw += 16384; bP0w += 8192; bP1w += 8192;

#pragma unroll 1
  for (int tt = 0; tt < 35; ++tt) {
    BODY14(fa, fb, ga, gb, 1, STAGE14(2, 0, 0), VM4);
    BODY14(ga, gb, fa, fb, 2, STAGE14(3, 512, 512), VM4);
    BODY14(fa, fb, ga, gb, 3, STAGE14(0, 16384, 8192), VM4);
    BODY14(ga, gb, fa, fb, 0, STAGE14(1, 16896, 8704), VM4);
    aPw += 32768; bP0w += 16384; bP1w += 16384;
  }
  BODY14(fa, fb, ga, gb, 1, STAGE14(2, 0, 0), VM4);
  BODY14(ga, gb, fa, fb, 2, STAGE14(3, 512, 512), VM4);
  BODY14(fa, fb, ga, gb, 3, ;, VM0);
  LGK0;
  SB;
  MFMA32(ga, gb);

  // ---- epilogue (no atomics in v14 path):
  // C/D mapping col = lane&15, row = (lane>>4)*4 + reg  [m89-verified]
  if (ATOMIC) {
#pragma unroll
    for (int m = 0; m < 8; ++m)
#pragma unroll
      for (int n = 0; n < 4; ++n) {
        int col = bn2 * 256 + wn * 64 + n * 16 + l15;
        int row0 = bm * 256 + wm * 128 + m * 16 + lhi * 4;
#pragma unroll
        for (int j = 0; j < 4; ++j)
          atomicAdd(&C[(size_t)(row0 + j) * OUT_F + col], acc[m][n][j]);
      }
  } else if (khalf == 1) {
#pragma unroll
    for (int m = 0; m < 8; ++m)
#pragma unroll
      for (int n = 0; n < 4; ++n) {
        int col = bn2 * 256 + wn * 64 + n * 16 + l15;
        int row0 = bm * 256 + wm * 128 + m * 16 + lhi * 4;
#pragma unroll
        for (int j = 0; j < 4; ++j)
          C[(size_t)(row0 + j) * OUT_F + col] = acc[m][n][j];
      }
  } else {
    float* Pt = P + (size_t)(bm * 4 + bn2) * 65536;
    int cl = wn * 64 + l15;            // local col base (+n*16)
    int rl = wm * 128 + lhi * 4;       // local row base (+m*16+j)
#pragma unroll
    for (int m = 0; m < 8; ++m)
#pragma unroll
      for (int n = 0; n < 4; ++n)
#pragma unroll
        for (int j = 0; j < 4; ++j)
          Pt[(size_t)(rl + m * 16 + j) * 256 + cl + n * 16] = acc[m][n][j];
  }
}

// --------------------------------------------------------- split-K reduction
__global__ __launch_bounds__(256) void reduce2(
    const float* __restrict__ P, float* __restrict__ C) {
  const int NG = M_ROWS * OUT_F / 4;   // 2M f32x4 groups
  for (int g = blockIdx.x * 256 + threadIdx.x; g < NG; g += gridDim.x * 256) {
    int row = g >> 8;                  // 256 groups per row
    int c4 = g & 255;
    int bm = row >> 8, bn2 = c4 >> 6;
    int r = row & 255, cl = (c4 & 63) * 4;
    f32x4 p = *(const f32x4*)(P + (size_t)(bm * 4 + bn2) * 65536 + r * 256 + cl);
    f32x4* o = (f32x4*)(C + (size_t)row * OUT_F + c4 * 4);
    *o += p;
  }
}

// ------------------------------------------------ naive fallback (insurance)
__global__ __launch_bounds__(256) void kan_naive(
    const float* __restrict__ x, const float* __restrict__ grid,
    const float* __restrict__ bw, const float* __restrict__ sw,
    const float* __restrict__ sc, float* __restrict__ out) {
  __shared__ float s_act[IN_F];
  __shared__ float s_bas[IN_F * 8];
  int n = blockIdx.x;
  for (int i = threadIdx.x; i < IN_F; i += 256) {
    float xv = x[(size_t)n * IN_F + i];
    float g[12];
    const float* gp = grid + i * 12;
#pragma unroll
    for (int t = 0; t < 12; ++t) g[t] = gp[t];
    float b[11];
#pragma unroll
    for (int j = 0; j < 11; ++j)
      b[j] = (xv >= g[j] && xv < g[j + 1]) ? 1.0f : 0.0f;
#pragma unroll
    for (int k = 1; k <= 3; ++k)
#pragma unroll
      for (int j = 0; j < 11 - k; ++j) {
        float left = (xv - g[j]) / (g[j + k] - g[j]);
        float right = (g[j + k + 1] - xv) / (g[j + k + 1] - g[j + 1]);
        b[j] = left * b[j] + right * b[j + 1];
      }
    s_act[i] = xv / (1.0f + __expf(-xv));
#pragma unroll
    for (int c = 0; c < 8; ++c) s_bas[i * 8 + c] = b[c];
  }
  __syncthreads();
  for (int o = threadIdx.x; o < OUT_F; o += 256) {
    float acc = 0.f;
    const float* bwo = bw + (size_t)o * IN_F;
    const float* swo = sw + (size_t)o * IN_F * 8;
    const float* sco = sc + (size_t)o * IN_F;
    for (int i = 0; i < IN_F; ++i) {
      acc += s_act[i] * bwo[i];
      float p = 0.f;
#pragma unroll
      for (int c = 0; c < 8; ++c) p += s_bas[i * 8 + c] * swo[i * 8 + c];
      acc += p * sco[i];
    }
    out[(size_t)n * OUT_F + o] = acc;
  }
}

// ---------------------------------------------------------------- launch
extern "C" void kernel_launch(void* const* d_in, const int* in_sizes, int n_in,
                              void* d_out, int out_size, void* d_ws, size_t ws_size,
                              hipStream_t stream) {
  const float* x  = (const float*)d_in[0];
  const float* grid = (const float*)d_in[1];
  const float* bw = (const float*)d_in[2];
  const float* sw = (const float*)d_in[3];
  const float* sc = (const float*)d_in[4];
  float* out = (float*)d_out;

  const size_t Bbytes = (size_t)OUT_F * KTOT * 2;              // 18.9 MB
  const size_t Abytes = (size_t)M_ROWS * KTOT * 2;             // 151 MB
  const size_t Pbytes = (size_t)32 * 4 * 65536 * 4;            // 32 MB
  const size_t rowBytes = (size_t)KTOT * 2;

  if (ws_size >= Bbytes + Abytes + Pbytes) {
    // ---- full path: split-K with direct stores + reduce (no atomics)
    __hip_bfloat16* Bp = (__hip_bfloat16*)d_ws;
    __hip_bfloat16* Ap = (__hip_bfloat16*)((char*)d_ws + Bbytes);
    float* Pp = (float*)((char*)d_ws + Bbytes + Abytes);

    pack_b<<<OUT_F * 128 / 256, 256, 0, stream>>>(bw, sw, sc, Bp);
    expand_a<<<(M_ROWS / 16) * 8, 256, 0, stream>>>(x, grid, Ap, 0, M_ROWS);
    gemm_v14<0><<<(M_ROWS / 256) * 8, 512, 0, stream>>>(Ap, Bp, out, Pp);
    reduce2<<<2048, 256, 0, stream>>>(Pp, out);
  } else if (ws_size >= Bbytes + 256 * rowBytes) {
    // ---- chunked atomic fallback (R13 behavior, known-passing)
    __hip_bfloat16* Bp = (__hip_bfloat16*)d_ws;
    __hip_bfloat16* Ap = (__hip_bfloat16*)((char*)d_ws + Bbytes);
    size_t arows = (ws_size - Bbytes) / rowBytes;
    int chunk = (int)((arows / 256) * 256);
    if (chunk > M_ROWS) chunk = M_ROWS;

    hipMemsetAsync(d_out, 0, (size_t)out_size * sizeof(float), stream);
    pack_b<<<OUT_F * 128 / 256, 256, 0, stream>>>(bw, sw, sc, Bp);
    for (int r0 = 0; r0 < M_ROWS; r0 += chunk) {
      int rows = M_ROWS - r0 < chunk ? M_ROWS - r0 : chunk;
      expand_a<<<(rows / 16) * 8, 256, 0, stream>>>(x, grid, Ap, r0, rows);
      gemm_v14<1><<<(rows / 256) * 8, 512, 0, stream>>>(Ap, Bp,
                                                        out + (size_t)r0 * OUT_F,
                                                        (float*)Ap /*unused*/);
    }
  } else {
    kan_naive<<<M_ROWS, 256, 0, stream>>>(x, grid, bw, sw, sc, out);
  }
}

// Round 15
// 192.273 us; speedup vs baseline: 1.1326x; 1.0009x over previous
//
#include <hip/hip_runtime.h>
#include <hip/hip_bf16.h>

#define IN_F 1024
#define OUT_F 1024
#define KTOT (IN_F * 9)   // 9216: channel-major, k = c*1024 + i, c=0 is silu
#define M_ROWS 8192

#define BK 64
#define NT (KTOT / BK)    // 144 kt64-tiles; 72 per K-half (split-K=2)
#define NT_H (NT / 2)

#define A_TILE_E 16384    // elements per A kt64-tile of a 256-row panel (32 KB)
#define B_TILE_E 8192     // elements per B kt64-tile of a 128-col panel (16 KB)

typedef short bf16x8 __attribute__((ext_vector_type(8)));
typedef int   i32x4  __attribute__((ext_vector_type(4)));
typedef float f32x4  __attribute__((ext_vector_type(4)));

#define AS1 __attribute__((address_space(1)))
#define AS3 __attribute__((address_space(3)))

// ---------------------------------------------------------------- basis eval
__device__ __forceinline__ void kan_basis_fast(
    float xv, const float* __restrict__ g,
    const float* __restrict__ inv1, const float* __restrict__ inv2,
    const float* __restrict__ inv3, float* __restrict__ out) {
  float b[11];
#pragma unroll
  for (int j = 0; j < 11; ++j)
    b[j] = (xv >= g[j] && xv < g[j + 1]) ? 1.0f : 0.0f;
#pragma unroll
  for (int j = 0; j < 10; ++j)
    b[j] = (xv - g[j]) * inv1[j] * b[j] + (g[j + 2] - xv) * inv1[j + 1] * b[j + 1];
#pragma unroll
  for (int j = 0; j < 9; ++j)
    b[j] = (xv - g[j]) * inv2[j] * b[j] + (g[j + 3] - xv) * inv2[j + 1] * b[j + 1];
#pragma unroll
  for (int j = 0; j < 8; ++j)
    b[j] = (xv - g[j]) * inv3[j] * b[j] + (g[j + 4] - xv) * inv3[j + 1] * b[j + 1];
#pragma unroll
  for (int j = 0; j < 8; ++j) out[j] = b[j];
}

// ------------------------------------------------- A expansion (fp32 -> bf16)
// Frag-ordered A (verified R9-R14): frag = (((bm*NT+kt)*4+wm4)*4+m)*2+kk,
// lane = lhi*16+l15 holds A[row][k=kt*64+kk*32+lhi*8+j].
__global__ __launch_bounds__(256) void expand_a(
    const float* __restrict__ x, const float* __restrict__ grid,
    __hip_bfloat16* __restrict__ A, int row0, int nrows) {
  const int tid = threadIdx.x;
  const int lane = tid & 63;
  const int wvx = tid >> 6;            // 0..3 : i-subblock
  const int l15 = lane & 15;
  const int lhi = lane >> 4;

  const int nb = blockIdx.x >> 3;      // 16-row group (local)
  const int ib = blockIdx.x & 7;       // 128-wide i group
  const int n_l = nb * 16 + l15;       // local row
  const int i0 = ib * 128 + wvx * 32 + lhi * 8;

  const int bm = n_l >> 8, wm = (n_l >> 6) & 3, m = (n_l >> 4) & 3;

  float g[12];
  const float* gp = grid + (size_t)i0 * 12;   // rows identical by construction
#pragma unroll
  for (int j = 0; j < 12; ++j) g[j] = gp[j];
  float inv1[11], inv2[10], inv3[9];
#pragma unroll
  for (int j = 0; j < 11; ++j) inv1[j] = 1.0f / (g[j + 1] - g[j]);
#pragma unroll
  for (int j = 0; j < 10; ++j) inv2[j] = 1.0f / (g[j + 2] - g[j]);
#pragma unroll
  for (int j = 0; j < 9; ++j)  inv3[j] = 1.0f / (g[j + 3] - g[j]);

  const float* xp = x + (size_t)(row0 + n_l) * IN_F + i0;
  float xs[8];
  *(f32x4*)&xs[0] = *(const f32x4*)xp;
  *(f32x4*)&xs[4] = *(const f32x4*)(xp + 4);

  bf16x8 out[9];
#pragma unroll
  for (int j = 0; j < 8; ++j) {
    float xv = xs[j];
    float bas[8];
    kan_basis_fast(xv, g, inv1, inv2, inv3, bas);
    float s = xv / (1.0f + __expf(-xv));
    out[0][j] = (short)__bfloat16_as_ushort(__float2bfloat16(s));
#pragma unroll
    for (int c = 0; c < 8; ++c)
      out[c + 1][j] = (short)__bfloat16_as_ushort(__float2bfloat16(bas[c]));
  }

#pragma unroll
  for (int c = 0; c < 9; ++c) {
    int k0 = c * IN_F + i0;            // wave-uniform kt,kk per c
    int kt = k0 >> 6;
    int kk = (k0 >> 5) & 1;
    size_t frag = ((((size_t)bm * NT + kt) * 4 + wm) * 4 + m) * 2 + kk;
    *(bf16x8*)(A + frag * 512 + lane * 8) = out[c];
  }
}

// --------------------------------------------------- B packing (fp32 -> bf16)
// Frag-ordered B (verified R11-R14): frag = ((obn*NT+kt)*8+colg)*2+kk over
// 128-col panels obn (0..7).
__global__ __launch_bounds__(256) void pack_b(
    const float* __restrict__ bw, const float* __restrict__ sw,
    const float* __restrict__ sc, __hip_bfloat16* __restrict__ B) {
  const int tid = threadIdx.x;
  const int lane = tid & 63;
  const int wid = blockIdx.x * 4 + (tid >> 6);   // 0..2047
  const int og = wid >> 5;           // 0..63: o-group of 16
  const int ib32 = wid & 31;         // 0..31: 32-wide i block
  const int obn = og >> 3, colg = og & 7;
  const int l15 = lane & 15, lhi = lane >> 4;
  const int o = og * 16 + l15;
  const int i0 = ib32 * 32 + lhi * 8;

  float bwv[8], scv[8];
  const float* bp = bw + (size_t)o * IN_F + i0;
  const float* sp = sc + (size_t)o * IN_F + i0;
  *(f32x4*)&bwv[0] = *(const f32x4*)bp;
  *(f32x4*)&bwv[4] = *(const f32x4*)(bp + 4);
  *(f32x4*)&scv[0] = *(const f32x4*)sp;
  *(f32x4*)&scv[4] = *(const f32x4*)(sp + 4);

  bf16x8 out[9];
#pragma unroll
  for (int j = 0; j < 8; ++j) {
    out[0][j] = (short)__bfloat16_as_ushort(__float2bfloat16(bwv[j]));
    const float* swp = sw + ((size_t)o * IN_F + i0 + j) * 8;
    float swv[8];
    *(f32x4*)&swv[0] = *(const f32x4*)swp;
    *(f32x4*)&swv[4] = *(const f32x4*)(swp + 4);
#pragma unroll
    for (int c = 0; c < 8; ++c)
      out[c + 1][j] = (short)__bfloat16_as_ushort(__float2bfloat16(swv[c] * scv[j]));
  }

#pragma unroll
  for (int c = 0; c < 9; ++c) {
    int kt = c * 16 + (ib32 >> 1);     // k0 = c*1024 + ib32*32
    int kk = ib32 & 1;
    size_t frag = ((size_t)obn * NT + kt) * 16 + colg * 2 + kk;
    *(bf16x8*)(B + frag * 512 + lane * 8) = out[c];
  }
}

// -------------------------------------------------------------- bf16 GEMM BT
// v15 = v14's 256x256/BK=32/split-K=2 + DOUBLE-STEP body: ONE barrier per
// kt64 (2 kt32 tiles), halving sync overhead. Per step: {STAGE next kt64
// (8 vm, issued first -> max vmcnt window); READ ga(t+1); lgkm(12) [fa
// ready]; MFMA(t); lgkm(0); MFMA(t+1); vmcnt(0); barrier; READ fa(t+2)}.
// 4-slot 32KB ring; epilogue: kh=1 stores C, kh=0 stores P; reduce2 C+=P.

__device__ __forceinline__ void gld16(const __hip_bfloat16* g, __hip_bfloat16* l) {
  __builtin_amdgcn_global_load_lds((AS1 void*)g, (AS3 void*)l, 16, 0, 0);
}

#define DSRO(dst, addr, IMM)                                               \
  asm volatile("ds_read_b128 %0, %1 offset:" #IMM : "=v"(dst) : "v"(addr))

#define SB __builtin_amdgcn_sched_barrier(0)

#define READ_A8(d, aA) do {                                                \
    DSRO(d[0], aA, 0);     DSRO(d[1], aA, 1024);                           \
    DSRO(d[2], aA, 2048);  DSRO(d[3], aA, 3072);                           \
    DSRO(d[4], aA, 4096);  DSRO(d[5], aA, 5120);                           \
    DSRO(d[6], aA, 6144);  DSRO(d[7], aA, 7168);                           \
  } while (0)
#define READ_B4(d, bA) do {                                                \
    DSRO(d[0], bA, 0);     DSRO(d[1], bA, 1024);                           \
    DSRO(d[2], bA, 2048);  DSRO(d[3], bA, 3072);                           \
  } while (0)

#define MFMA32(sA, sB) do {                                                \
    __builtin_amdgcn_s_setprio(1);                                         \
    _Pragma("unroll")                                                      \
    for (int m_ = 0; m_ < 8; ++m_)                                         \
      _Pragma("unroll")                                                    \
      for (int n_ = 0; n_ < 4; ++n_)                                       \
        acc[m_][n_] = __builtin_amdgcn_mfma_f32_16x16x32_bf16(             \
            sA[m_], sB[n_], acc[m_][n_], 0, 0, 0);                         \
    __builtin_amdgcn_s_setprio(0);                                         \
  } while (0)

#define STAGE15(SLOT, GA_, GB_) do {                                       \
    __hip_bfloat16* d_ = ldsP + (SLOT) * 16384;                            \
    gld16(aPw + (GA_),         d_ + wv * 512);                             \
    gld16(aPw + (GA_) + 8192,  d_ + 4096 + wv * 512);                      \
    gld16(bP0w + (GB_),        d_ + 8192 + wv * 512);                      \
    gld16(bP1w + (GB_),        d_ + 12288 + wv * 512);                     \
  } while (0)

#define VM0 asm volatile("s_waitcnt vmcnt(0)" ::: "memory")
#define LGK0 asm volatile("s_waitcnt lgkmcnt(0)" ::: "memory")
#define LGK12 asm volatile("s_waitcnt lgkmcnt(12)" ::: "memory")

// double-step: fa/fb preloaded (tile t, slot SA implied); ga <- tile t+1
// (slot S1_); stage next kt64 into S2_,S3_; preload fa <- tile t+2 (S2_)
#define DSTEP(S1_, S2_, S3_, GA_, GB_) do {                                \
    STAGE15(S2_, (GA_), (GB_));                                            \
    STAGE15(S3_, (GA_) + 512, (GB_) + 512);                                \
    READ_A8(ga, aRdB + (S1_) * 32768u);                                    \
    READ_B4(gb, bRdB + (S1_) * 32768u);                                    \
    SB;                                                                    \
    LGK12; SB;                                                             \
    MFMA32(fa, fb);                                                        \
    SB;                                                                    \
    LGK0; SB;                                                              \
    MFMA32(ga, gb);                                                        \
    SB;                                                                    \
    VM0; SB;                                                               \
    __builtin_amdgcn_s_barrier(); SB;                                      \
    READ_A8(fa, aRdB + (S2_) * 32768u);                                    \
    READ_B4(fb, bRdB + (S2_) * 32768u);                                    \
    SB;                                                                    \
  } while (0)

template <int ATOMIC>
__global__ __launch_bounds__(512, 2) void gemm_v15(
    const __hip_bfloat16* __restrict__ A, const __hip_bfloat16* __restrict__ B,
    float* __restrict__ C, float* __restrict__ P) {
  __shared__ __align__(16) __hip_bfloat16 S[4][16384];  // 4 x 32 KB

  // bijective XCD swizzle: 8 consecutive L share bm -> A-panel L2 reuse
  const int nwg = gridDim.x;            // (M/256)*8, %8 == 0
  const int q = nwg >> 3;
  const int L = (blockIdx.x & 7) * q + (blockIdx.x >> 3);
  const int bm = L >> 3;
  const int khalf = (L >> 2) & 1;
  const int bn2 = L & 3;                // 256-col block

  const int tid = threadIdx.x;
  const int lane = tid & 63;
  const int wv = tid >> 6;            // 0..7
  const int wm = wv >> 2;             // 0..1 (128-row half)
  const int wn = wv & 3;              // 0..3 (64-col quarter)
  const int l15 = lane & 15, lhi = lane >> 4;

  const __hip_bfloat16* aPw =
      A + ((size_t)bm * NT + khalf * NT_H) * A_TILE_E + wv * 1024 + lane * 8;
  const __hip_bfloat16* bP0w =
      B + ((size_t)(2 * bn2) * NT + khalf * NT_H) * B_TILE_E + wv * 1024 + lane * 8;
  const __hip_bfloat16* bP1w =
      B + ((size_t)(2 * bn2 + 1) * NT + khalf * NT_H) * B_TILE_E + wv * 1024 + lane * 8;
  __hip_bfloat16* ldsP = &S[0][0];

  const uint32_t ldsB = (uint32_t)(uintptr_t)(AS3 const void*)&S[0][0];
  const uint32_t aRdB = ldsB + wm * 8192 + lane * 16;
  const uint32_t bRdB = ldsB + 16384 + wn * 4096 + lane * 16;

  f32x4 acc[8][4];
#pragma unroll
  for (int m = 0; m < 8; ++m)
#pragma unroll
    for (int n = 0; n < 4; ++n) acc[m][n] = f32x4{0.f, 0.f, 0.f, 0.f};

  bf16x8 fa[8], fb[4];   // even-tile frags (preloaded)
  bf16x8 ga[8], gb[4];   // odd-tile frags

  // ---- prologue: stage kt64#0 -> slots 0,1; publish; preload fa <- tile 0
  STAGE15(0, 0, 0);
  STAGE15(1, 512, 512);
  VM0; SB;
  __builtin_amdgcn_s_barrier(); SB;
  READ_A8(fa, aRdB);
  READ_B4(fb, bRdB);                                  // lgkm 12
  SB;
  aPw += 16384; bP0w += 8192; bP1w += 8192;           // -> kt64 #1

#pragma unroll 1
  for (int tt = 0; tt < 35; ++tt) {                   // steps i = 2tt, 2tt+1
    DSTEP(1, 2, 3, 0, 0);                             // stage kt64 #(2tt+1)
    DSTEP(3, 0, 1, 16384, 8192);                      // stage kt64 #(2tt+2)
    aPw += 32768; bP0w += 16384; bP1w += 16384;
  }
  // step i = 70: tiles 140,141 (s0,s1); stage kt64#71 (tiles 142,143) -> s2,s3
  DSTEP(1, 2, 3, 0, 0);
  // step i = 71: tiles 142 (fa, s2), 143 (s3); no stage
  READ_A8(ga, aRdB + 3 * 32768u);
  READ_B4(gb, bRdB + 3 * 32768u);
  SB;
  LGK12; SB;
  MFMA32(fa, fb);
  SB;
  LGK0; SB;
  MFMA32(ga, gb);
  SB;

  // ---- epilogue: C/D mapping col = lane&15, row = (lane>>4)*4 + reg [m89]
  if (ATOMIC) {
#pragma unroll
    for (int m = 0; m < 8; ++m)
#pragma unroll
      for (int n = 0; n < 4; ++n) {
        int col = bn2 * 256 + wn * 64 + n * 16 + l15;
        int row0 = bm * 256 + wm * 128 + m * 16 + lhi * 4;
#pragma unroll
        for (int j = 0; j < 4; ++j)
          atomicAdd(&C[(size_t)(row0 + j) * OUT_F + col], acc[m][n][j]);
      }
  } else if (khalf == 1) {
#pragma unroll
    for (int m = 0; m < 8; ++m)
#pragma unroll
      for (int n = 0; n < 4; ++n) {
        int col = bn2 * 256 + wn * 64 + n * 16 + l15;
        int row0 = bm * 256 + wm * 128 + m * 16 + lhi * 4;
#pragma unroll
        for (int j = 0; j < 4; ++j)
          C[(size_t)(row0 + j) * OUT_F + col] = acc[m][n][j];
      }
  } else {
    float* Pt = P + (size_t)(bm * 4 + bn2) * 65536;
    int cl = wn * 64 + l15;
    int rl = wm * 128 + lhi * 4;
#pragma unroll
    for (int m = 0; m < 8; ++m)
#pragma unroll
      for (int n = 0; n < 4; ++n)
#pragma unroll
        for (int j = 0; j < 4; ++j)
          Pt[(size_t)(rl + m * 16 + j) * 256 + cl + n * 16] = acc[m][n][j];
  }
}

// --------------------------------------------------------- split-K reduction
__global__ __launch_bounds__(256) void reduce2(
    const float* __restrict__ P, float* __restrict__ C) {
  const int NG = M_ROWS * OUT_F / 4;   // 2M f32x4 groups
  for (int g = blockIdx.x * 256 + threadIdx.x; g < NG; g += gridDim.x * 256) {
    int row = g >> 8;                  // 256 groups per row
    int c4 = g & 255;
    int bm = row >> 8, bn2 = c4 >> 6;
    int r = row & 255, cl = (c4 & 63) * 4;
    f32x4 p = *(const f32x4*)(P + (size_t)(bm * 4 + bn2) * 65536 + r * 256 + cl);
    f32x4* o = (f32x4*)(C + (size_t)row * OUT_F + c4 * 4);
    *o += p;
  }
}

// ------------------------------------------------ naive fallback (insurance)
__global__ __launch_bounds__(256) void kan_naive(
    const float* __restrict__ x, const float* __restrict__ grid,
    const float* __restrict__ bw, const float* __restrict__ sw,
    const float* __restrict__ sc, float* __restrict__ out) {
  __shared__ float s_act[IN_F];
  __shared__ float s_bas[IN_F * 8];
  int n = blockIdx.x;
  for (int i = threadIdx.x; i < IN_F; i += 256) {
    float xv = x[(size_t)n * IN_F + i];
    float g[12];
    const float* gp = grid + i * 12;
#pragma unroll
    for (int t = 0; t < 12; ++t) g[t] = gp[t];
    float b[11];
#pragma unroll
    for (int j = 0; j < 11; ++j)
      b[j] = (xv >= g[j] && xv < g[j + 1]) ? 1.0f : 0.0f;
#pragma unroll
    for (int k = 1; k <= 3; ++k)
#pragma unroll
      for (int j = 0; j < 11 - k; ++j) {
        float left = (xv - g[j]) / (g[j + k] - g[j]);
        float right = (g[j + k + 1] - xv) / (g[j + k + 1] - g[j + 1]);
        b[j] = left * b[j] + right * b[j + 1];
      }
    s_act[i] = xv / (1.0f + __expf(-xv));
#pragma unroll
    for (int c = 0; c < 8; ++c) s_bas[i * 8 + c] = b[c];
  }
  __syncthreads();
  for (int o = threadIdx.x; o < OUT_F; o += 256) {
    float acc = 0.f;
    const float* bwo = bw + (size_t)o * IN_F;
    const float* swo = sw + (size_t)o * IN_F * 8;
    const float* sco = sc + (size_t)o * IN_F;
    for (int i = 0; i < IN_F; ++i) {
      acc += s_act[i] * bwo[i];
      float p = 0.f;
#pragma unroll
      for (int c = 0; c < 8; ++c) p += s_bas[i * 8 + c] * swo[i * 8 + c];
      acc += p * sco[i];
    }
    out[(size_t)n * OUT_F + o] = acc;
  }
}

// ---------------------------------------------------------------- launch
extern "C" void kernel_launch(void* const* d_in, const int* in_sizes, int n_in,
                              void* d_out, int out_size, void* d_ws, size_t ws_size,
                              hipStream_t stream) {
  const float* x  = (const float*)d_in[0];
  const float* grid = (const float*)d_in[1];
  const float* bw = (const float*)d_in[2];
  const float* sw = (const float*)d_in[3];
  const float* sc = (const float*)d_in[4];
  float* out = (float*)d_out;

  const size_t Bbytes = (size_t)OUT_F * KTOT * 2;              // 18.9 MB
  const size_t Abytes = (size_t)M_ROWS * KTOT * 2;             // 151 MB
  const size_t Pbytes = (size_t)32 * 4 * 65536 * 4;            // 32 MB
  const size_t rowBytes = (size_t)KTOT * 2;

  if (ws_size >= Bbytes + Abytes + Pbytes) {
    // ---- full path: split-K with direct stores + reduce (no atomics)
    __hip_bfloat16* Bp = (__hip_bfloat16*)d_ws;
    __hip_bfloat16* Ap = (__hip_bfloat16*)((char*)d_ws + Bbytes);
    float* Pp = (float*)((char*)d_ws + Bbytes + Abytes);

    pack_b<<<OUT_F * 128 / 256, 256, 0, stream>>>(bw, sw, sc, Bp);
    expand_a<<<(M_ROWS / 16) * 8, 256, 0, stream>>>(x, grid, Ap, 0, M_ROWS);
    gemm_v15<0><<<(M_ROWS / 256) * 8, 512, 0, stream>>>(Ap, Bp, out, Pp);
    reduce2<<<2048, 256, 0, stream>>>(Pp, out);
  } else if (ws_size >= Bbytes + 256 * rowBytes) {
    // ---- chunked atomic fallback (known-passing)
    __hip_bfloat16* Bp = (__hip_bfloat16*)d_ws;
    __hip_bfloat16* Ap = (__hip_bfloat16*)((char*)d_ws + Bbytes);
    size_t arows = (ws_size - Bbytes) / rowBytes;
    int chunk = (int)((arows / 256) * 256);
    if (chunk > M_ROWS) chunk = M_ROWS;

    hipMemsetAsync(d_out, 0, (size_t)out_size * sizeof(float), stream);
    pack_b<<<OUT_F * 128 / 256, 256, 0, stream>>>(bw, sw, sc, Bp);
    for (int r0 = 0; r0 < M_ROWS; r0 += chunk) {
      int rows = M_ROWS - r0 < chunk ? M_ROWS - r0 : chunk;
      expand_a<<<(rows / 16) * 8, 256, 0, stream>>>(x, grid, Ap, r0, rows);
      gemm_v15<1><<<(rows / 256) * 8, 512, 0, stream>>>(Ap, Bp,
                                                        out + (size_t)r0 * OUT_F,
                                                        (float*)Ap /*unused*/);
    }
  } else {
    kan_naive<<<M_ROWS, 256, 0, stream>>>(x, grid, bw, sw, sc, out);
  }
}

// Round 16
// 184.765 us; speedup vs baseline: 1.1786x; 1.0406x over previous
//
#include <hip/hip_runtime.h>
#include <hip/hip_bf16.h>

#define IN_F 1024
#define OUT_F 1024
#define KTOT (IN_F * 9)   // 9216: channel-major, k = c*1024 + i, c=0 is silu
#define M_ROWS 8192

#define BM 256
#define BN 128
#define BK 64
#define NT (KTOT / BK)    // 144 K-tiles

// frag-ordered buffers: A tile (bm,kt) = 32 contiguous KB (32 frags of 1 KB:
// [wm][m][kk]); B tile (bn,kt) = 16 contiguous KB (16 frags: [colg][kk]).
// Within a frag, lane = lhi*16+l15 holds 16 B: row/col = l15-group, k = lhi*8+j.
#define A_TILE_E 16384    // elements per A K-tile (32 KB)
#define B_TILE_E 8192     // elements per B K-tile (16 KB)

typedef short bf16x8 __attribute__((ext_vector_type(8)));
typedef int   i32x4  __attribute__((ext_vector_type(4)));
typedef float f32x4  __attribute__((ext_vector_type(4)));

#define AS1 __attribute__((address_space(1)))
#define AS3 __attribute__((address_space(3)))

// ---------------------------------------------------------------- basis eval
__device__ __forceinline__ void kan_basis_fast(
    float xv, const float* __restrict__ g,
    const float* __restrict__ inv1, const float* __restrict__ inv2,
    const float* __restrict__ inv3, float* __restrict__ out) {
  float b[11];
#pragma unroll
  for (int j = 0; j < 11; ++j)
    b[j] = (xv >= g[j] && xv < g[j + 1]) ? 1.0f : 0.0f;
#pragma unroll
  for (int j = 0; j < 10; ++j)
    b[j] = (xv - g[j]) * inv1[j] * b[j] + (g[j + 2] - xv) * inv1[j + 1] * b[j + 1];
#pragma unroll
  for (int j = 0; j < 9; ++j)
    b[j] = (xv - g[j]) * inv2[j] * b[j] + (g[j + 3] - xv) * inv2[j + 1] * b[j + 1];
#pragma unroll
  for (int j = 0; j < 8; ++j)
    b[j] = (xv - g[j]) * inv3[j] * b[j] + (g[j + 4] - xv) * inv3[j + 1] * b[j + 1];
#pragma unroll
  for (int j = 0; j < 8; ++j) out[j] = b[j];
}

// ------------------------------------------------- A expansion (fp32 -> bf16)
// Frag-ordered A (verified R9-R15): frag = (((bm*NT+kt)*4+wm)*4+m)*2+kk,
// lane = lhi*16+l15 holds A[row][k=kt*64+kk*32+lhi*8+j]. Each wave store per
// channel c is one contiguous 1 KB fragment write.
__device__ __forceinline__ void expand_body(
    const float* __restrict__ x, const float* __restrict__ grid,
    __hip_bfloat16* __restrict__ A, int row0, int vbid, int tid) {
  const int lane = tid & 63;
  const int wvx = tid >> 6;            // 0..3 : i-subblock
  const int l15 = lane & 15;
  const int lhi = lane >> 4;

  const int nb = vbid >> 3;            // 16-row group (local)
  const int ib = vbid & 7;             // 128-wide i group
  const int n_l = nb * 16 + l15;       // local row
  const int i0 = ib * 128 + wvx * 32 + lhi * 8;

  const int bm = n_l >> 8, wm = (n_l >> 6) & 3, m = (n_l >> 4) & 3;

  float g[12];
  const float* gp = grid + (size_t)i0 * 12;   // rows identical by construction
#pragma unroll
  for (int j = 0; j < 12; ++j) g[j] = gp[j];
  float inv1[11], inv2[10], inv3[9];
#pragma unroll
  for (int j = 0; j < 11; ++j) inv1[j] = 1.0f / (g[j + 1] - g[j]);
#pragma unroll
  for (int j = 0; j < 10; ++j) inv2[j] = 1.0f / (g[j + 2] - g[j]);
#pragma unroll
  for (int j = 0; j < 9; ++j)  inv3[j] = 1.0f / (g[j + 3] - g[j]);

  const float* xp = x + (size_t)(row0 + n_l) * IN_F + i0;
  float xs[8];
  *(f32x4*)&xs[0] = *(const f32x4*)xp;
  *(f32x4*)&xs[4] = *(const f32x4*)(xp + 4);

  bf16x8 out[9];
#pragma unroll
  for (int j = 0; j < 8; ++j) {
    float xv = xs[j];
    float bas[8];
    kan_basis_fast(xv, g, inv1, inv2, inv3, bas);
    float s = xv / (1.0f + __expf(-xv));
    out[0][j] = (short)__bfloat16_as_ushort(__float2bfloat16(s));
#pragma unroll
    for (int c = 0; c < 8; ++c)
      out[c + 1][j] = (short)__bfloat16_as_ushort(__float2bfloat16(bas[c]));
  }

#pragma unroll
  for (int c = 0; c < 9; ++c) {
    int k0 = c * IN_F + i0;            // wave-uniform kt,kk per c
    int kt = k0 >> 6;
    int kk = (k0 >> 5) & 1;
    size_t frag = ((((size_t)bm * NT + kt) * 4 + wm) * 4 + m) * 2 + kk;
    *(bf16x8*)(A + frag * 512 + lane * 8) = out[c];
  }
}

__global__ __launch_bounds__(256) void expand_a(
    const float* __restrict__ x, const float* __restrict__ grid,
    __hip_bfloat16* __restrict__ A, int row0, int nrows) {
  expand_body(x, grid, A, row0, blockIdx.x, threadIdx.x);
}

// --------------------------------------------------- B packing (fp32 -> bf16)
// Frag-ordered B (verified R11-R15): frag = ((bn*NT+kt)*8+colg)*2+kk.
__device__ __forceinline__ void pack_body(
    const float* __restrict__ bw, const float* __restrict__ sw,
    const float* __restrict__ sc, __hip_bfloat16* __restrict__ B,
    int vbid, int tid) {
  const int lane = tid & 63;
  const int wid = vbid * 4 + (tid >> 6);   // 0..2047
  const int og = wid >> 5;           // 0..63: o-group of 16
  const int ib32 = wid & 31;         // 0..31: 32-wide i block
  const int bn = og >> 3, colg = og & 7;
  const int l15 = lane & 15, lhi = lane >> 4;
  const int o = og * 16 + l15;
  const int i0 = ib32 * 32 + lhi * 8;

  float bwv[8], scv[8];
  const float* bp = bw + (size_t)o * IN_F + i0;
  const float* sp = sc + (size_t)o * IN_F + i0;
  *(f32x4*)&bwv[0] = *(const f32x4*)bp;
  *(f32x4*)&bwv[4] = *(const f32x4*)(bp + 4);
  *(f32x4*)&scv[0] = *(const f32x4*)sp;
  *(f32x4*)&scv[4] = *(const f32x4*)(sp + 4);

  bf16x8 out[9];
#pragma unroll
  for (int j = 0; j < 8; ++j) {
    out[0][j] = (short)__bfloat16_as_ushort(__float2bfloat16(bwv[j]));
    const float* swp = sw + ((size_t)o * IN_F + i0 + j) * 8;
    float swv[8];
    *(f32x4*)&swv[0] = *(const f32x4*)swp;
    *(f32x4*)&swv[4] = *(const f32x4*)(swp + 4);
#pragma unroll
    for (int c = 0; c < 8; ++c)
      out[c + 1][j] = (short)__bfloat16_as_ushort(__float2bfloat16(swv[c] * scv[j]));
  }

#pragma unroll
  for (int c = 0; c < 9; ++c) {
    int kt = c * 16 + (ib32 >> 1);     // k0 = c*1024 + ib32*32
    int kk = ib32 & 1;
    size_t frag = ((size_t)bn * NT + kt) * 16 + colg * 2 + kk;
    *(bf16x8*)(B + frag * 512 + lane * 8) = out[c];
  }
}

__global__ __launch_bounds__(256) void pack_b(
    const float* __restrict__ bw, const float* __restrict__ sw,
    const float* __restrict__ sc, __hip_bfloat16* __restrict__ B) {
  pack_body(bw, sw, sc, B, blockIdx.x, threadIdx.x);
}

// ---------------------------------------- fused prep: expand (4096) + pack (512)
__global__ __launch_bounds__(256) void prep_fused(
    const float* __restrict__ x, const float* __restrict__ grid,
    __hip_bfloat16* __restrict__ A,
    const float* __restrict__ bw, const float* __restrict__ sw,
    const float* __restrict__ sc, __hip_bfloat16* __restrict__ B) {
  if (blockIdx.x < 4096)
    expand_body(x, grid, A, 0, blockIdx.x, threadIdx.x);
  else
    pack_body(bw, sw, sc, B, blockIdx.x - 4096, threadIdx.x);
}

// -------------------------------------------------------------- bf16 GEMM BT
// v11 (VERIFIED BEST, R11: gemm 133 us, total 183.4): v7 schedule (3-slot
// ring staged 2 ahead, 6 DMA/tile, vmcnt(6), lgkm 8/0, ONE barrier/tile,
// reg-level frag double-buffer) over FRAG-ORDERED A and B: staging =
// contiguous 1 KB wave-ops, linear LDS, NO swizzle; every ds_read_b128 =
// frag_base + lane*16 (canonical even pattern). At the LDS b128-issue
// ceiling: 24 reads/wave/tile x 144 tiles ~ 2217 cyc/tile measured.

__device__ __forceinline__ void gld16(const __hip_bfloat16* g, __hip_bfloat16* l) {
  __builtin_amdgcn_global_load_lds((AS1 void*)g, (AS3 void*)l, 16, 0, 0);
}

// inline-asm LDS read: opaque to alias analysis -> no compiler vmcnt(0) drain
__device__ __forceinline__ bf16x8 dsr128(uint32_t addr) {
  i32x4 r;
  asm volatile("ds_read_b128 %0, %1" : "=v"(r) : "v"(addr));
  return __builtin_bit_cast(bf16x8, r);
}

#define SB __builtin_amdgcn_sched_barrier(0)

#define SLOT_B 49152   // bytes per LDS slot (A 32K + B 16K)
#define SLOT_E 24576   // elements per LDS slot

#define READ_FRAGS(dA, dB, slot, h) do {                                   \
    uint32_t s_ = ldsB + (uint32_t)(slot) * SLOT_B;                        \
    _Pragma("unroll")                                                      \
    for (int m_ = 0; m_ < 4; ++m_) dA[m_] = dsr128(s_ + aOff[h][m_]);      \
    _Pragma("unroll")                                                      \
    for (int n_ = 0; n_ < 4; ++n_) dB[n_] = dsr128(s_ + bOff[h][n_]);      \
  } while (0)

#define MFMA_BURST(sA, sB) do {                                            \
    __builtin_amdgcn_s_setprio(1);                                         \
    _Pragma("unroll")                                                      \
    for (int m_ = 0; m_ < 4; ++m_)                                         \
      _Pragma("unroll")                                                    \
      for (int n_ = 0; n_ < 4; ++n_)                                       \
        acc[m_][n_] = __builtin_amdgcn_mfma_f32_16x16x32_bf16(             \
            sA[m_], sB[n_], acc[m_][n_], 0, 0, 0);                         \
    __builtin_amdgcn_s_setprio(0);                                         \
  } while (0)

// stage tile t into slot: 4 A wave-ops + 2 B wave-ops, all 1 KB contiguous
#define STAGE_T(slot, t) do {                                              \
    __hip_bfloat16* d_ = ldsP + (slot) * SLOT_E;                           \
    const __hip_bfloat16* aT_ = aG + (size_t)(t) * A_TILE_E;               \
    const __hip_bfloat16* bT_ = bG + (size_t)(t) * B_TILE_E;               \
    gld16(aT_,         d_ + dstE);                                         \
    gld16(aT_ + 4096,  d_ + dstE + 4096);                                  \
    gld16(aT_ + 8192,  d_ + dstE + 8192);                                  \
    gld16(aT_ + 12288, d_ + dstE + 12288);                                 \
    gld16(bT_,         d_ + 16384 + dstE);                                 \
    gld16(bT_ + 4096,  d_ + 16384 + dstE + 4096);                          \
  } while (0)

#define TILE_FULL(t) do {                                                  \
    const int nxt_ = cur == 2 ? 0 : cur + 1;                               \
    const int stg_ = cur == 0 ? 2 : cur - 1;                               \
    READ_FRAGS(ga, gb, cur, 1);                      /* lgkm 16 */         \
    STAGE_T(stg_, (t) + 2);                          /* vm -> 12 */        \
    SB;                                                                    \
    asm volatile("s_waitcnt lgkmcnt(8)" ::: "memory"); SB;                 \
    MFMA_BURST(fa, fb);                                                    \
    SB;                                                                    \
    asm volatile("s_waitcnt lgkmcnt(0)" ::: "memory"); SB;                 \
    asm volatile("s_waitcnt vmcnt(6)" ::: "memory"); SB;                   \
    __builtin_amdgcn_s_barrier(); SB;                /* publish t+1 */     \
    READ_FRAGS(fa, fb, nxt_, 0);                     /* lgkm 8 */          \
    SB;                                                                    \
    MFMA_BURST(ga, gb);                                                    \
    SB;                                                                    \
    cur = nxt_;                                                            \
  } while (0)

#define TILE_NT2() do {                                                    \
    const int nxt_ = cur == 2 ? 0 : cur + 1;                               \
    READ_FRAGS(ga, gb, cur, 1);                                            \
    SB;                                                                    \
    asm volatile("s_waitcnt lgkmcnt(8)" ::: "memory"); SB;                 \
    MFMA_BURST(fa, fb);                                                    \
    SB;                                                                    \
    asm volatile("s_waitcnt lgkmcnt(0)" ::: "memory"); SB;                 \
    asm volatile("s_waitcnt vmcnt(0)" ::: "memory"); SB;                   \
    __builtin_amdgcn_s_barrier(); SB;                                      \
    READ_FRAGS(fa, fb, nxt_, 0);                                           \
    SB;                                                                    \
    MFMA_BURST(ga, gb);                                                    \
    SB;                                                                    \
    cur = nxt_;                                                            \
  } while (0)

#define TILE_LAST() do {                                                   \
    READ_FRAGS(ga, gb, cur, 1);                                            \
    SB;                                                                    \
    asm volatile("s_waitcnt lgkmcnt(8)" ::: "memory"); SB;                 \
    MFMA_BURST(fa, fb);                                                    \
    SB;                                                                    \
    asm volatile("s_waitcnt lgkmcnt(0)" ::: "memory"); SB;                 \
    MFMA_BURST(ga, gb);                                                    \
    SB;                                                                    \
  } while (0)

__global__ __launch_bounds__(512, 2) void gemm_v11(
    const __hip_bfloat16* __restrict__ A, const __hip_bfloat16* __restrict__ B,
    float* __restrict__ C) {
  __shared__ __align__(16) __hip_bfloat16 S[3][SLOT_E];  // 3 x (A 32K | B 16K)

  // T1 bijective XCD swizzle: 8 bn-blocks sharing an A-panel on one XCD
  const int nwg = gridDim.x;            // (M/256)*8, %8 == 0
  const int q = nwg >> 3;
  const int L = (blockIdx.x & 7) * q + (blockIdx.x >> 3);
  const int bm = L >> 3, bn = L & 7;

  const int tid = threadIdx.x;
  const int lane = tid & 63;
  const int wv = tid >> 6;            // 0..7
  const int wm = wv >> 1;             // 0..3 (64-row group)
  const int wn = wv & 1;              // 0..1 (64-col group)
  const int l15 = lane & 15, lhi = lane >> 4;

  // ---- staging bases: contiguous per-tile panels, per-lane 16 B
  const __hip_bfloat16* aG = A + (size_t)bm * NT * A_TILE_E + (wv * 64 + lane) * 8;
  const __hip_bfloat16* bG = B + (size_t)bn * NT * B_TILE_E + (wv * 64 + lane) * 8;
  __hip_bfloat16* ldsP = &S[0][0];
  const int dstE = wv * 512;          // wave's element offset within a 4096-chunk

  // ---- fragment read byte-offsets: frag_idx*1024 + lane*16
  const uint32_t ldsB = (uint32_t)(uintptr_t)(AS3 const void*)&S[0][0];
  uint32_t aOff[2][4], bOff[2][4];
#pragma unroll
  for (int h = 0; h < 2; ++h)
#pragma unroll
    for (int m = 0; m < 4; ++m) {
      aOff[h][m] = (uint32_t)((wm * 8 + m * 2 + h) * 1024 + lane * 16);
      bOff[h][m] = (uint32_t)(32768 + ((wn * 4 + m) * 2 + h) * 1024 + lane * 16);
    }

  f32x4 acc[4][4];
#pragma unroll
  for (int m = 0; m < 4; ++m)
#pragma unroll
    for (int n = 0; n < 4; ++n) acc[m][n] = f32x4{0.f, 0.f, 0.f, 0.f};

  bf16x8 fa[4], fb[4];   // kk0 frags (preloaded)
  bf16x8 ga[4], gb[4];   // kk1 frags

  // ---- prologue: stage tiles 0,1; publish slot0; preload kk0(0)
  STAGE_T(0, 0);
  STAGE_T(1, 1);
  asm volatile("s_waitcnt vmcnt(6)" ::: "memory");   // tile 0 landed
  SB;
  __builtin_amdgcn_s_barrier();
  SB;
  READ_FRAGS(fa, fb, 0, 0);                          // lgkm 8
  SB;

  int cur = 0;
  for (int t = 0; t < NT - 2; ++t) TILE_FULL(t);
  TILE_NT2();                                        // t = NT-2
  TILE_LAST();                                       // t = NT-1

  // epilogue: C/D mapping col = lane&15, row = (lane>>4)*4 + reg [m89]
#pragma unroll
  for (int m = 0; m < 4; ++m)
#pragma unroll
    for (int n = 0; n < 4; ++n) {
      int col = bn * BN + wn * 64 + n * 16 + l15;
      int row0 = bm * BM + wm * 64 + m * 16 + lhi * 4;
#pragma unroll
      for (int j = 0; j < 4; ++j)
        C[(size_t)(row0 + j) * OUT_F + col] = acc[m][n][j];
    }
}

// ------------------------------------------------ naive fallback (insurance)
__global__ __launch_bounds__(256) void kan_naive(
    const float* __restrict__ x, const float* __restrict__ grid,
    const float* __restrict__ bw, const float* __restrict__ sw,
    const float* __restrict__ sc, float* __restrict__ out) {
  __shared__ float s_act[IN_F];
  __shared__ float s_bas[IN_F * 8];
  int n = blockIdx.x;
  for (int i = threadIdx.x; i < IN_F; i += 256) {
    float xv = x[(size_t)n * IN_F + i];
    float g[12];
    const float* gp = grid + i * 12;
#pragma unroll
    for (int t = 0; t < 12; ++t) g[t] = gp[t];
    float b[11];
#pragma unroll
    for (int j = 0; j < 11; ++j)
      b[j] = (xv >= g[j] && xv < g[j + 1]) ? 1.0f : 0.0f;
#pragma unroll
    for (int k = 1; k <= 3; ++k)
#pragma unroll
      for (int j = 0; j < 11 - k; ++j) {
        float left = (xv - g[j]) / (g[j + k] - g[j]);
        float right = (g[j + k + 1] - xv) / (g[j + k + 1] - g[j + 1]);
        b[j] = left * b[j] + right * b[j + 1];
      }
    s_act[i] = xv / (1.0f + __expf(-xv));
#pragma unroll
    for (int c = 0; c < 8; ++c) s_bas[i * 8 + c] = b[c];
  }
  __syncthreads();
  for (int o = threadIdx.x; o < OUT_F; o += 256) {
    float acc = 0.f;
    const float* bwo = bw + (size_t)o * IN_F;
    const float* swo = sw + (size_t)o * IN_F * 8;
    const float* sco = sc + (size_t)o * IN_F;
    for (int i = 0; i < IN_F; ++i) {
      acc += s_act[i] * bwo[i];
      float p = 0.f;
#pragma unroll
      for (int c = 0; c < 8; ++c) p += s_bas[i * 8 + c] * swo[i * 8 + c];
      acc += p * sco[i];
    }
    out[(size_t)n * OUT_F + o] = acc;
  }
}

// ---------------------------------------------------------------- launch
extern "C" void kernel_launch(void* const* d_in, const int* in_sizes, int n_in,
                              void* d_out, int out_size, void* d_ws, size_t ws_size,
                              hipStream_t stream) {
  const float* x  = (const float*)d_in[0];
  const float* grid = (const float*)d_in[1];
  const float* bw = (const float*)d_in[2];
  const float* sw = (const float*)d_in[3];
  const float* sc = (const float*)d_in[4];
  float* out = (float*)d_out;

  const size_t Bbytes = (size_t)OUT_F * KTOT * 2;              // 18.9 MB
  const size_t Abytes = (size_t)M_ROWS * KTOT * 2;             // 151 MB
  const size_t rowBytes = (size_t)KTOT * 2;

  if (ws_size >= Bbytes + Abytes) {
    // ---- full path: fused prep (expand 4096 blocks + pack 512), then gemm
    __hip_bfloat16* Bp = (__hip_bfloat16*)d_ws;
    __hip_bfloat16* Ap = (__hip_bfloat16*)((char*)d_ws + Bbytes);

    prep_fused<<<4096 + 512, 256, 0, stream>>>(x, grid, Ap, bw, sw, sc, Bp);
    gemm_v11<<<(M_ROWS / BM) * 8, 512, 0, stream>>>(Ap, Bp, out);
  } else if (ws_size >= Bbytes + 256 * rowBytes) {
    // ---- chunked fallback (R11 behavior, known-passing)
    __hip_bfloat16* Bp = (__hip_bfloat16*)d_ws;
    __hip_bfloat16* Ap = (__hip_bfloat16*)((char*)d_ws + Bbytes);
    size_t arows = (ws_size - Bbytes) / rowBytes;
    int chunk = (int)((arows / 256) * 256);
    if (chunk > M_ROWS) chunk = M_ROWS;

    pack_b<<<OUT_F * 128 / 256, 256, 0, stream>>>(bw, sw, sc, Bp);
    for (int r0 = 0; r0 < M_ROWS; r0 += chunk) {
      int rows = M_ROWS - r0 < chunk ? M_ROWS - r0 : chunk;   // multiple of 256
      expand_a<<<(rows / 16) * 8, 256, 0, stream>>>(x, grid, Ap, r0, rows);
      gemm_v11<<<(rows / BM) * 8, 512, 0, stream>>>(Ap, Bp, out + (size_t)r0 * OUT_F);
    }
  } else {
    kan_naive<<<M_ROWS, 256, 0, stream>>>(x, grid, bw, sw, sc, out);
  }
}